// Round 6
// baseline (690.062 us; speedup 1.0000x reference)
//
#include <hip/hip_runtime.h>
#include <stdint.h>

typedef __bf16 bf16;
typedef __bf16 bf16x8 __attribute__((ext_vector_type(8)));
typedef float f32x4 __attribute__((ext_vector_type(4)));

enum { EPI_STORE = 0, EPI_BIAS_RELU = 1, EPI_VRED = 2 };

// async global->LDS, 16 bytes per lane; LDS dest = wave-uniform base + lane*16
__device__ __forceinline__ void gload16(const bf16* g, bf16* l) {
  __builtin_amdgcn_global_load_lds(
      (const __attribute__((address_space(1))) unsigned int*)g,
      (__attribute__((address_space(3))) unsigned int*)l, 16, 0, 0);
}

// C[M,N] = A[M,K] @ B[K,N], B supplied transposed (Bt[N,K]).
// SMALL-TILE / HIGH-TLP version: BM=64 x BN=128 x BK=32, 256 threads = 4 waves,
// wave tile 32x64 (acc[2][4]). Rationale: previous 128x256 tile capped L2/L4 at
// 512 blocks = 2 blocks/CU = 8 waves/CU (OccupancyPercent 21%) -- latency-bound
// with nothing to hide under. 2048 blocks + 25KB LDS + ~100 VGPR -> 4-6
// blocks/CU; TLP does the latency hiding, so depth-1 (2 LDS buffers) suffices.
// Counted vmcnt (never 0 mid-loop), per-block k-rotation (HBM de-phasing),
// chunk-XOR LDS swizzle (rule #21: swizzled global source, linear LDS dest,
// same XOR on read). A_F32: adj streamed f32 nontemporal, reg-staged with
// lag-1 commit (2 named pf sets; n must be even).
// Epilogue (STORE/BIAS_RELU): per-wave LDS bounce -> bf16x8 stores.
// EPI_VRED: v[col] = sum_rows adj_row0[row] * relu(C[row][col] + bias[col])
template<bool A_F32, int EPI>
__global__ __launch_bounds__(256, 4)
void gemm_bt(const void* __restrict__ Ap, const bf16* __restrict__ Btp,
             const float* __restrict__ bias, bf16* __restrict__ C,
             float* __restrict__ vpart, const float* __restrict__ adjp,
             int K, int ldA, int ldBt, int ldC,
             long sA, long sBt, long sC)
{
  constexpr int BM = 64, BN = 128, BK = 32;
  __shared__ __align__(16) char raw[24576];   // 2x(4K As + 8K Bs)
  auto Asb = [&](int b) -> bf16* { return (bf16*)(raw + b * 4096); };
  auto Bsb = [&](int b) -> bf16* { return (bf16*)(raw + 8192 + b * 8192); };
  __shared__ float a0s[BM];
  __shared__ float vsum[BN];

  const int tid  = threadIdx.x;
  const int lane = tid & 63;
  const int wid  = tid >> 6;
  const int wm   = wid >> 1;   // 0..1 : m half (32 rows)
  const int wn   = wid & 1;    // 0..1 : n half (64 cols)
  const int l15  = lane & 15;
  const int quad = lane >> 4;

  const int nb = blockIdx.x, mb = blockIdx.y, g = blockIdx.z;

  const long aoff = (long)g * sA + (long)mb * BM * ldA;
  const long boff = (long)g * sBt + (long)nb * BN * ldBt;

  if constexpr (EPI == EPI_VRED) {
    if (tid < BM) a0s[tid] = adjp[(long)g * sA + mb * BM + tid];  // adj[g][0][row]
    if (tid < BN) vsum[tid] = 0.f;
  }

  // staging geometry: thread covers row r = tid>>2 (0..63), 16B chunk c4.
  const int r   = tid >> 2;
  const int c4  = tid & 3;
  const int sw  = (r >> 1) & 3;
  const int kcs = (c4 ^ sw) << 3;   // swizzled chunk: gload SOURCE / f32 ds_write POS
  const int kcp = c4 << 3;          // plain chunk: f32 global loads
  const int csw = (quad ^ ((l15 >> 1) & 3)) << 3;  // read-side chunk position

  const int n  = K / BK;            // power of two (4 / 8 / 32), even
  const int nm = n - 1;
  const int off = (g * 11 + mb * 5 + nb * 3) & nm;      // per-block k rotation
  auto kof = [&](int s) { return ((s + off) & nm) * BK; };

  const bf16* Bg0 = Btp + boff;

  auto issueB = [&](int k0, int buf) {        // 2 gloads
    const bf16* Bg = Bg0 + k0;
    #pragma unroll
    for (int p = 0; p < 2; ++p)
      gload16(Bg + (long)(p * 64 + r) * ldBt + kcs, Bsb(buf) + p * 2048 + tid * 8);
  };
  auto issueAg = [&](int k0, int buf) {       // 1 gload
    const bf16* Ag = (const bf16*)Ap + aoff + k0;
    gload16(Ag + (long)r * ldA + kcs, Asb(buf) + tid * 8);
  };
  auto issueAf = [&](int k0, f32x4 (&pf)[2]) {  // 2 f32x4 reg loads
    const float* Ag = (const float*)Ap + aoff + k0;
    const f32x4* src = (const f32x4*)(Ag + (long)r * ldA + kcp);
    pf[0] = __builtin_nontemporal_load(src);      // adj: streamed once
    pf[1] = __builtin_nontemporal_load(src + 1);
  };
  auto commitAf = [&](f32x4 (&pf)[2], int buf) {
    f32x4 v0 = pf[0], v1 = pf[1];
    bf16x8 w;
    w[0]=(bf16)v0[0]; w[1]=(bf16)v0[1]; w[2]=(bf16)v0[2]; w[3]=(bf16)v0[3];
    w[4]=(bf16)v1[0]; w[5]=(bf16)v1[1]; w[6]=(bf16)v1[2]; w[7]=(bf16)v1[3];
    *(bf16x8*)(Asb(buf) + r * 32 + kcs) = w;      // swizzled position
  };

  f32x4 acc[2][4] = {};

  if constexpr (!A_F32) {
    // -------------- pure-bf16 path, depth-1 gload pipeline ----------------
    issueAg(kof(0), 0); issueB(kof(0), 0);
    for (int s = 0; s < n; ++s) {
      const int b = s & 1;
      if (s + 1 < n) { issueAg(kof(s + 1), b ^ 1); issueB(kof(s + 1), b ^ 1); }
      if (s + 1 < n) asm volatile("s_waitcnt vmcnt(3)" ::: "memory");  // tile s done
      else           asm volatile("s_waitcnt vmcnt(0)" ::: "memory");
      __builtin_amdgcn_s_barrier();            // tile s landed everywhere

      bf16x8 af[2], bfr[4];
      #pragma unroll
      for (int i = 0; i < 2; ++i)
        af[i] = *(const bf16x8*)(Asb(b) + (wm * 32 + i * 16 + l15) * 32 + csw);
      #pragma unroll
      for (int j = 0; j < 4; ++j)
        bfr[j] = *(const bf16x8*)(Bsb(b) + (wn * 64 + j * 16 + l15) * 32 + csw);
      asm volatile("s_waitcnt lgkmcnt(0)" ::: "memory");
      __builtin_amdgcn_s_barrier();            // everyone's reads done

      #pragma unroll
      for (int i = 0; i < 2; ++i)
        #pragma unroll
        for (int j = 0; j < 4; ++j)
          acc[i][j] = __builtin_amdgcn_mfma_f32_16x16x32_bf16(af[i], bfr[j], acc[i][j], 0, 0, 0);
    }
  } else {
    // ---------- f32-A path: lag-1 reg commit for A, depth-1 B (n even) ----
    f32x4 pfa[2], pfb[2];
    issueAf(kof(0), pfa); issueB(kof(0), 0);
    issueAf(kof(1), pfb);
    commitAf(pfa, 0);                          // compiler auto-waits A(0) regs
    asm volatile("s_waitcnt vmcnt(2)" ::: "memory");   // B(0) done, A(1) in flight
    asm volatile("s_waitcnt lgkmcnt(0)" ::: "memory");
    __builtin_amdgcn_s_barrier();

    auto bodyF = [&](int s, f32x4 (&pfI)[2], f32x4 (&pfC)[2]) {
      const int b = s & 1;
      if (s + 2 < n) issueAf(kof(s + 2), pfI);         // 2 ops
      if (s + 1 < n) issueB(kof(s + 1), b ^ 1);        // 2 ops
      if (s + 2 < n)      asm volatile("s_waitcnt vmcnt(4)" ::: "memory");
      else if (s + 1 < n) asm volatile("s_waitcnt vmcnt(2)" ::: "memory");
      else                asm volatile("s_waitcnt vmcnt(0)" ::: "memory");
      __builtin_amdgcn_s_barrier();            // tile s landed everywhere

      bf16x8 af[2], bfr[4];
      #pragma unroll
      for (int i = 0; i < 2; ++i)
        af[i] = *(const bf16x8*)(Asb(b) + (wm * 32 + i * 16 + l15) * 32 + csw);
      #pragma unroll
      for (int j = 0; j < 4; ++j)
        bfr[j] = *(const bf16x8*)(Bsb(b) + (wn * 64 + j * 16 + l15) * 32 + csw);
      if (s + 1 < n) commitAf(pfC, b ^ 1);     // cvt + ds_write tile s+1
      asm volatile("s_waitcnt lgkmcnt(0)" ::: "memory");
      __builtin_amdgcn_s_barrier();            // reads done + commit visible

      #pragma unroll
      for (int i = 0; i < 2; ++i)
        #pragma unroll
        for (int j = 0; j < 4; ++j)
          acc[i][j] = __builtin_amdgcn_mfma_f32_16x16x32_bf16(af[i], bfr[j], acc[i][j], 0, 0, 0);
    };
    for (int s = 0; s < n; s += 2) { bodyF(s, pfa, pfb); bodyF(s + 1, pfb, pfa); }
  }

  if constexpr (EPI == EPI_STORE || EPI == EPI_BIAS_RELU) {
    // per-wave LDS bounce: scalar bf16 scatter -> LDS, then bf16x8 stores.
    constexpr int LDW = 80;                    // row stride 160 B (16B-aligned)
    bf16* slab = (bf16*)(raw + wid * 5120);    // [32][80] bf16, wave-private
    #pragma unroll
    for (int j = 0; j < 4; ++j) {
      float bv = 0.f;
      if constexpr (EPI == EPI_BIAS_RELU) bv = bias[nb * BN + wn * 64 + j * 16 + l15];
      #pragma unroll
      for (int i = 0; i < 2; ++i)
        #pragma unroll
        for (int rr = 0; rr < 4; ++rr) {
          float v = acc[i][j][rr];
          if constexpr (EPI == EPI_BIAS_RELU) v = fmaxf(v + bv, 0.f);
          slab[(i * 16 + quad * 4 + rr) * LDW + j * 16 + l15] = (bf16)v;
        }
    }
    asm volatile("s_waitcnt lgkmcnt(0)" ::: "memory");   // in-wave ds visibility
    bf16* Cg = C + (long)g * sC + (long)(mb * BM + wm * 32) * ldC + nb * BN + wn * 64;
    #pragma unroll
    for (int t = 0; t < 4; ++t) {
      const int rowl = t * 8 + (lane >> 3);
      const int c8 = lane & 7;
      bf16x8 w = *(const bf16x8*)&slab[rowl * LDW + c8 * 8];
      *(bf16x8*)&Cg[(long)rowl * ldC + c8 * 8] = w;
    }
  } else {  // EPI_VRED: H2 never materialized
    __syncthreads();
    #pragma unroll
    for (int j = 0; j < 4; ++j) {
      const int col = wn * 64 + j * 16 + l15;
      const float bv = bias[col];
      float p = 0.f;
      #pragma unroll
      for (int i = 0; i < 2; ++i) {
        const int lr = wm * 32 + i * 16 + quad * 4;
        #pragma unroll
        for (int rr = 0; rr < 4; ++rr)
          p += fmaxf(acc[i][j][rr] + bv, 0.f) * a0s[lr + rr];
      }
      atomicAdd(&vsum[col], p);
    }
    __syncthreads();
    if (tid < BN)
      vpart[((long)g * 16 + mb) * 256 + nb * BN + tid] = vsum[tid];
  }
}

// Streaming f32 -> bf16 conversion (8 elems/thread/iter)
__global__ void cvt1(const float* __restrict__ src, bf16* __restrict__ dst, long n8)
{
  const long stride = (long)gridDim.x * blockDim.x;
  for (long i = (long)blockIdx.x * blockDim.x + threadIdx.x; i < n8; i += stride) {
    const f32x4* s = (const f32x4*)(src + i * 8);
    f32x4 v0 = s[0], v1 = s[1];
    bf16x8 w;
    w[0]=(bf16)v0[0]; w[1]=(bf16)v0[1]; w[2]=(bf16)v0[2]; w[3]=(bf16)v0[3];
    w[4]=(bf16)v1[0]; w[5]=(bf16)v1[1]; w[6]=(bf16)v1[2]; w[7]=(bf16)v1[3];
    *(bf16x8*)(dst + i * 8) = w;
  }
}

// Transpose + convert weights: W0t[h][k]=W0[k][h] (256x128), W1t[h][k]=W1[k][h] (256x256)
__global__ void prep_w(const float* __restrict__ W0, const float* __restrict__ W1,
                       bf16* __restrict__ W0t, bf16* __restrict__ W1t)
{
  const int idx = blockIdx.x * 256 + threadIdx.x;  // 0..65535
  if (idx < 256 * 128) {
    const int h = idx >> 7, k = idx & 127;
    W0t[idx] = (bf16)W0[k * 256 + h];
  }
  const int h = idx >> 8, k = idx & 255;
  W1t[idx] = (bf16)W1[k * 256 + h];
}

// Per graph: v = sum of 16 partials; h3 = relu(v@W2 + b2); out = h3@Wl + bl (all fp32)
__global__ void finish_k(const float* __restrict__ vpart, const float* __restrict__ W2,
                         const float* __restrict__ b2, const float* __restrict__ Wl,
                         const float* __restrict__ bl, float* __restrict__ out)
{
  const int b = blockIdx.x, t = threadIdx.x;
  __shared__ float v[256], h3[256];
  float s = 0.f;
  #pragma unroll
  for (int mb = 0; mb < 16; ++mb) s += vpart[((long)b * 16 + mb) * 256 + t];
  v[t] = s;
  __syncthreads();
  float z = b2[t];
  for (int k = 0; k < 256; ++k) z += v[k] * W2[k * 256 + t];
  h3[t] = fmaxf(z, 0.f);
  __syncthreads();
  if (t < 128) {
    float o = bl[t];
    for (int h = 0; h < 256; ++h) o += h3[h] * Wl[h * 128 + t];
    out[(long)b * 128 + t] = o;
  }
}

extern "C" void kernel_launch(void* const* d_in, const int* in_sizes, int n_in,
                              void* d_out, int out_size, void* d_ws, size_t ws_size,
                              hipStream_t stream) {
  const float* embs = (const float*)d_in[0];  // [64,1024,128]
  const float* adj  = (const float*)d_in[1];  // [64,1024,1024]
  const float* W0   = (const float*)d_in[2];  // [128,256]
  const float* b0   = (const float*)d_in[3];
  const float* W1   = (const float*)d_in[4];  // [256,256]
  const float* b1   = (const float*)d_in[5];
  const float* W2   = (const float*)d_in[6];  // [256,256]
  const float* b2   = (const float*)d_in[7];
  const float* Wl   = (const float*)d_in[8];  // [256,128]
  const float* bl   = (const float*)d_in[9];
  float* out = (float*)d_out;

  char* ws = (char*)d_ws;
  bf16*  Zt     = (bf16*)(ws);                 // [64][256][1024] bf16 (Z0t then Z1t)
  bf16*  Hb     = (bf16*)(ws + 33554432);      // [64][1024][256] bf16 (H1)
  bf16*  W0t    = (bf16*)(ws + 67108864);      // [256][128]
  bf16*  W1t    = (bf16*)(ws + 67174400);      // [256][256]
  float* vpart  = (float*)(ws + 67305472);     // [64][16][256] f32
  bf16*  embs16 = (bf16*)(ws + 100663296);     // [64][1024][128] bf16, 16 MB

  prep_w<<<256, 256, 0, stream>>>(W0, W1, W0t, W1t);
  cvt1<<<2048, 256, 0, stream>>>(embs, embs16, 64L * 1024 * 128 / 8);

  // L1: Z0t[h,n] = sum_k W0t[h,k]*embs16[n,k] : M=256,N=1024,K=128
  gemm_bt<false, EPI_STORE><<<dim3(8, 4, 64), 256, 0, stream>>>(
      W0t, embs16, nullptr, Zt, nullptr, nullptr,
      128, 128, 128, 1024, 0L, 131072L, 262144L);

  // L2: H1[n,h] = relu(sum_m adj[n,m]*Z0t[h,m] + b0[h]) : M=1024,N=256,K=1024
  gemm_bt<true, EPI_BIAS_RELU><<<dim3(2, 16, 64), 256, 0, stream>>>(
      adj, Zt, b0, Hb, nullptr, nullptr,
      1024, 1024, 1024, 256, 1048576L, 262144L, 262144L);

  // L3: Z1t[h,n] = sum_k W1t[h,k]*H1[n,k] : M=256,N=1024,K=256
  gemm_bt<false, EPI_STORE><<<dim3(8, 4, 64), 256, 0, stream>>>(
      W1t, Hb, nullptr, Zt, nullptr, nullptr,
      256, 256, 256, 1024, 0L, 262144L, 262144L);

  // L4: vpart[g,mb,h] = sum_{rows in mb} adj[g,0,row]*relu(adj@Z1t + b1)[row,h]
  gemm_bt<true, EPI_VRED><<<dim3(2, 16, 64), 256, 0, stream>>>(
      adj, Zt, b1, nullptr, vpart, adj,
      1024, 1024, 1024, 256, 1048576L, 262144L, 0L);

  finish_k<<<64, 256, 0, stream>>>(vpart, W2, b2, Wl, bl, out);
}